// Round 4
// baseline (65.320 us; speedup 1.0000x reference)
//
#include <hip/hip_runtime.h>
#include <math.h>

// Problem constants (match reference)
#define BN 32
#define RR 13
#define CC 13
#define AA 5
#define KK 20
#define CELLSZ 25
#define NN (RR * CC * AA)      // 845 cells per batch
#define TOT (NN * CELLSZ)      // 21125 floats per batch image
#define THRESH 0.5f
#define NMS_TH 0.4f
#define NT 1024                // 16 waves

// One block per batch. Stage batch into LDS, decode in-place, per-class greedy
// NMS by independent waves over a compacted LDS candidate pool, coalesced
// stage-out. No workspace, no atomics to global, single dispatch.
__global__ __launch_bounds__(NT) void region_kernel(
        const float* __restrict__ x,
        const float* __restrict__ bias,
        float* __restrict__ out)
{
    __shared__ float sraw[TOT];            // 84.5 KB: raw cells -> output image
    __shared__ int   pcnt;                 // candidate pool count
    __shared__ int   kcnt[KK];             // per-class candidate count
    __shared__ int   ctag[NN], cidx[NN];   // class, cell index
    __shared__ float csc[NN], px1[NN], py1[NN], px2[NN], py2[NN], par[NN];

    const int b   = blockIdx.x;
    const int tid = threadIdx.x;
    const float* xb = x   + (size_t)b * TOT;
    float*       ob = out + (size_t)b * TOT;

    if (tid == 0) pcnt = 0;
    if (tid < KK) kcnt[tid] = 0;

    // ---- coalesced stage-in ----
    for (int i = tid; i < TOT; i += NT) sraw[i] = xb[i];
    __syncthreads();

    // ---- decode: one cell per thread (845 < 1024) ----
    if (tid < NN) {
        const int n  = tid;
        int r   = n / (CC * AA);
        int rem = n - r * (CC * AA);
        int c   = rem / AA;
        int a   = rem - c * AA;
        float* t = sraw + n * CELLSZ;      // lane-stride 25 vs 32 banks: 2-way, free

        float bx  = (1.f / (1.f + expf(-t[0])) + (float)c) / (float)CC;
        float by  = (1.f / (1.f + expf(-t[1])) + (float)r) / (float)RR;
        float bw  = expf(t[2]) * bias[2 * a]     / (float)RR;
        float bh  = expf(t[3]) * bias[2 * a + 1] / (float)CC;
        float obj = 1.f / (1.f + expf(-t[4]));

        float l[KK];
        float m = t[5];
#pragma unroll
        for (int k = 0; k < KK; ++k) { l[k] = t[5 + k]; m = fmaxf(m, l[k]); }
        float s = 0.f;
#pragma unroll
        for (int k = 0; k < KK; ++k) s += expf(l[k] - m);
        int km = 0;                        // first index attaining the max
#pragma unroll
        for (int k = 1; k < KK; ++k) if (l[k] > l[km]) km = k;

        // Only the argmax class can exceed 0.5 (softmax sums to 1, obj < 1).
        // expf(0)=1 exactly, so p == reference's obj*(expf(l_km-m)/s) bitwise.
        float p = obj * (1.0f / s);

        t[0] = bx; t[1] = by; t[2] = bw; t[3] = bh; t[4] = obj;
#pragma unroll
        for (int k = 0; k < KK; ++k) t[5 + k] = 0.f;   // kept scores patched later

        if (p > THRESH) {
            int slot = atomicAdd(&pcnt, 1);            // LDS atomic, rare
            atomicAdd(&kcnt[km], 1);
            ctag[slot] = km; cidx[slot] = n; csc[slot] = p;
            float x1 = bx - bw * 0.5f, y1 = by - bh * 0.5f;
            px1[slot] = x1; py1[slot] = y1;
            px2[slot] = x1 + bw; py2[slot] = y1 + bh;
            par[slot] = bw * bh;
        }
    }
    __syncthreads();

    // ---- per-class greedy NMS: wave w handles classes w, w+16 ----
    const int mtot = pcnt;
    const int wave = tid >> 6;
    const int lane = tid & 63;
    const int T    = (mtot + 63) >> 6;     // pool slots per lane (<= 14)

    for (int k = wave; k < KK; k += (NT / 64)) {
        if (kcnt[k] == 0) continue;
        unsigned alive = 0;
        for (int tt = 0; tt < T; ++tt) {
            int j = lane + (tt << 6);
            if (j < mtot && ctag[j] == k) alive |= (1u << tt);
        }
        while (true) {
            // local argmax: (score desc, n asc) == reference stable argsort
            float bs = -1.f; int bnn = 0x7fffffff; int bg = -1;
            for (int tt = 0; tt < T; ++tt) {
                if ((alive >> tt) & 1u) {
                    int j = lane + (tt << 6);
                    float sc = csc[j]; int nn = cidx[j];
                    if (sc > bs || (sc == bs && nn < bnn)) { bs = sc; bnn = nn; bg = j; }
                }
            }
#pragma unroll
            for (int off = 32; off; off >>= 1) {       // wave butterfly
                float os = __shfl_xor(bs, off);
                int   on = __shfl_xor(bnn, off);
                int   og = __shfl_xor(bg, off);
                if (os > bs || (os == bs && on < bnn)) { bs = os; bnn = on; bg = og; }
            }
            if (bg < 0) break;                         // nothing alive

            float X1 = px1[bg], Y1 = py1[bg], X2 = px2[bg], Y2 = py2[bg], AR = par[bg];
            if ((bg & 63) == lane) {                   // owner keeps winner
                sraw[bnn * CELLSZ + 5 + k] = bs;       // patch score in LDS
                alive &= ~(1u << (bg >> 6));
            }
            for (int tt = 0; tt < T; ++tt) {           // suppress overlaps
                int j = lane + (tt << 6);
                if (((alive >> tt) & 1u) && j != bg) {
                    float iw = fmaxf(0.f, fminf(X2, px2[j]) - fmaxf(X1, px1[j]));
                    float ih = fmaxf(0.f, fminf(Y2, py2[j]) - fmaxf(Y1, py1[j]));
                    float inter = iw * ih;
                    float uni   = AR + par[j] - inter;
                    if (inter / fmaxf(uni, 1e-9f) > NMS_TH) alive &= ~(1u << tt);
                }
            }
        }
    }
    __syncthreads();

    // ---- coalesced stage-out ----
    for (int i = tid; i < TOT; i += NT) ob[i] = sraw[i];
}

extern "C" void kernel_launch(void* const* d_in, const int* in_sizes, int n_in,
                              void* d_out, int out_size, void* d_ws, size_t ws_size,
                              hipStream_t stream) {
    const float* x    = (const float*)d_in[0];
    const float* bias = (const float*)d_in[1];
    float* out = (float*)d_out;

    region_kernel<<<BN, NT, 0, stream>>>(x, bias, out);
}